// Round 4
// baseline (562.891 us; speedup 1.0000x reference)
//
#include <hip/hip_runtime.h>

#define N_NODES 100000
#define DIM     128
#define RR      100
#define NE      400000
#define NBLK    196   // ceil(N_NODES / 512)

typedef float  floatx4 __attribute__((ext_vector_type(4)));
typedef __bf16 bf16x8  __attribute__((ext_vector_type(8)));

static __device__ __forceinline__ unsigned short f2b(float f) {
    union { float f; unsigned int i; } v; v.f = f;
    unsigned int u = v.i;
    unsigned int r = (u + 0x7fffu + ((u >> 16) & 1u)) >> 16;   // RNE
    return (unsigned short)r;
}
static __device__ __forceinline__ float b2f(unsigned int u16) {
    union { unsigned int i; float f; } v; v.i = u16 << 16; return v.f;
}

// ---- per-dst degree ------------------------------------------------------
__global__ void k_deg(const int* __restrict__ dst, int* __restrict__ deg, int E) {
    int e = blockIdx.x * 256 + threadIdx.x;
    if (e < E) atomicAdd(&deg[dst[e]], 1);
}

// ---- 2-level exclusive scan over deg[N] ----------------------------------
__global__ void k_scan_block(const int* __restrict__ deg, int* __restrict__ bsum) {
    __shared__ int sm[256];
    int b = blockIdx.x, t = threadIdx.x;
    int i0 = b * 512 + 2 * t;
    int a = (i0     < N_NODES) ? deg[i0]     : 0;
    int c = (i0 + 1 < N_NODES) ? deg[i0 + 1] : 0;
    sm[t] = a + c;
    __syncthreads();
    for (int s = 128; s > 0; s >>= 1) { if (t < s) sm[t] += sm[t + s]; __syncthreads(); }
    if (t == 0) bsum[b] = sm[0];
}

__global__ void k_scan_top(const int* __restrict__ bsum, int* __restrict__ boff) {
    __shared__ int sm[256];
    int t = threadIdx.x;
    int v = (t < NBLK) ? bsum[t] : 0;
    sm[t] = v;
    __syncthreads();
    for (int s = 1; s < 256; s <<= 1) {
        int u = (t >= s) ? sm[t - s] : 0;
        __syncthreads();
        sm[t] += u;
        __syncthreads();
    }
    if (t < NBLK) boff[t] = sm[t] - v;   // exclusive
}

__global__ void k_scan_down(const int* __restrict__ deg, const int* __restrict__ boff,
                            int* __restrict__ off) {
    __shared__ int sm[256];
    int b = blockIdx.x, t = threadIdx.x;
    int i0 = b * 512 + 2 * t;
    int a = (i0     < N_NODES) ? deg[i0]     : 0;
    int c = (i0 + 1 < N_NODES) ? deg[i0 + 1] : 0;
    int ts = a + c;
    sm[t] = ts;
    __syncthreads();
    for (int s = 1; s < 256; s <<= 1) {
        int u = (t >= s) ? sm[t - s] : 0;
        __syncthreads();
        sm[t] += u;
        __syncthreads();
    }
    int base = boff[b] + (sm[t] - ts);
    if (i0     < N_NODES) off[i0]     = base;
    if (i0 + 1 < N_NODES) off[i0 + 1] = base + a;
    if (b == 0 && t == 0) off[N_NODES] = NE;
}

// ---- scatter edges into dst-sorted CSR: desc = {src, et, eidx, norm} ----
__global__ void k_scatter(const int* __restrict__ src, const int* __restrict__ dst,
                          const int* __restrict__ et, const int* __restrict__ off,
                          int* __restrict__ cursor, int4* __restrict__ edesc, int E) {
    int e = blockIdx.x * 256 + threadIdx.x;
    if (e >= E) return;
    int d = dst[e];
    int pos = off[d] + atomicAdd(&cursor[d], 1);
    edesc[pos] = make_int4(src[e], et[e], e, 0);
}

// ---- schlichtkrull norm via per-node O(deg^2) type matching -------------
__global__ void k_norm2(const int* __restrict__ off, int4* __restrict__ edesc) {
    int d = blockIdx.x * 256 + threadIdx.x;
    if (d >= N_NODES) return;
    int p0 = off[d], p1 = off[d + 1];
    const int* ed = (const int*)edesc;
    for (int i = p0; i < p1; ++i) {
        int ti = ed[4 * i + 1];
        int c = 0;
        for (int j = p0; j < p1; ++j) c += (ed[4 * j + 1] == ti) ? 1 : 0;
        ((int*)edesc)[4 * i + 3] = __float_as_int(1.0f / (float)c);
    }
}

// ---- x0 = relu(ent + ent_bias) fp32 -> bf16 ------------------------------
__global__ void k_x0(const float* __restrict__ ent, const float* __restrict__ entb,
                     unsigned short* __restrict__ x, int total) {
    int i = blockIdx.x * 256 + threadIdx.x;
    if (i < total) {
        float v = ent[i] + entb[i & (DIM - 1)];
        x[i] = f2b(v > 0.0f ? v : 0.0f);
    }
}

// ---- weight prep: wt[m=outcol][k 0..639] = (bases stacked ; root), bf16 --
__global__ void k_prep(const float* __restrict__ bases1, const float* __restrict__ root1,
                       const float* __restrict__ bases2, const float* __restrict__ root2,
                       const float* __restrict__ rel,
                       unsigned short* __restrict__ wt1, unsigned short* __restrict__ wt2,
                       unsigned short* __restrict__ relb) {
    int i = blockIdx.x * 256 + threadIdx.x;
    if (i < 128 * 640) {
        int m = i / 640, k = i % 640;
        float v1, v2;
        if (k < 512) {
            int b = k >> 7, kin = k & 127;
            v1 = bases1[(b * 128 + kin) * 128 + m];
            v2 = bases2[(b * 128 + kin) * 128 + m];
        } else {
            int kin = k - 512;
            v1 = root1[kin * 128 + m];
            v2 = root2[kin * 128 + m];
        }
        wt1[i] = f2b(v1);
        wt2[i] = f2b(v2);
    }
    if (i < RR * DIM) relb[i] = f2b(rel[i]);
}

// ---- fused aggregate + GEMM ---------------------------------------------
// Block: 512 thr (8 waves), 64 dst nodes. Phase A: each wave aggregates 8
// nodes' S-rows (4 chunks x 128, fp32 acc) from x gathers into LDS (bf16,
// MFMA-A layout, xor-swizzled). Phase B: MFMA K=640: chunks 0..3 from LDS,
// chunk 4 = X rows direct from global; B read direct (L2-resident 160 KB).
__global__ __launch_bounds__(512) void k_fused(const unsigned short* __restrict__ X,
                                               const int4* __restrict__ edesc,
                                               const int* __restrict__ off,
                                               const float* __restrict__ comp,
                                               const unsigned short* __restrict__ WT,
                                               const float* __restrict__ bias,
                                               unsigned short* __restrict__ out,
                                               int do_relu) {
    __shared__ __align__(16) unsigned short Sl[4 * 64 * 128];   // 64 KB

    const int t = threadIdx.x;
    const int wid = t >> 6, lane = t & 63;
    const int rbase = blockIdx.x * 64;

    // ---------------- phase A ----------------
    {
        const int l = lane;
        const int ch16 = l >> 2;                    // 16B-chunk index 0..15
        for (int i = 0; i < 8; ++i) {
            int nl = wid * 8 + i;
            int d = rbase + nl;
            float2 acc[4];
#pragma unroll
            for (int b = 0; b < 4; ++b) acc[b] = make_float2(0.0f, 0.0f);
            if (d < N_NODES) {
                int p = off[d], pe = off[d + 1];
                for (; p + 1 < pe; p += 2) {        // 2-deep pipeline
                    int4 e0 = edesc[p], e1 = edesc[p + 1];
                    unsigned int xa = *(const unsigned int*)(X + (size_t)e0.x * 128 + 2 * l);
                    unsigned int xb = *(const unsigned int*)(X + (size_t)e1.x * 128 + 2 * l);
                    float4 ca = *(const float4*)(comp + e0.y * 4);
                    float4 cb = *(const float4*)(comp + e1.y * 4);
                    float wa = __int_as_float(e0.w), wb = __int_as_float(e1.w);
                    float a0 = b2f(xa & 0xffffu), a1 = b2f(xa >> 16);
                    float b0 = b2f(xb & 0xffffu), b1 = b2f(xb >> 16);
                    float k0 = wa * ca.x, k1 = wa * ca.y, k2 = wa * ca.z, k3 = wa * ca.w;
                    float m0 = wb * cb.x, m1 = wb * cb.y, m2 = wb * cb.z, m3 = wb * cb.w;
                    acc[0].x += k0 * a0 + m0 * b0;  acc[0].y += k0 * a1 + m0 * b1;
                    acc[1].x += k1 * a0 + m1 * b0;  acc[1].y += k1 * a1 + m1 * b1;
                    acc[2].x += k2 * a0 + m2 * b0;  acc[2].y += k2 * a1 + m2 * b1;
                    acc[3].x += k3 * a0 + m3 * b0;  acc[3].y += k3 * a1 + m3 * b1;
                }
                if (p < pe) {
                    int4 e0 = edesc[p];
                    unsigned int xa = *(const unsigned int*)(X + (size_t)e0.x * 128 + 2 * l);
                    float4 ca = *(const float4*)(comp + e0.y * 4);
                    float wa = __int_as_float(e0.w);
                    float a0 = b2f(xa & 0xffffu), a1 = b2f(xa >> 16);
                    float k0 = wa * ca.x, k1 = wa * ca.y, k2 = wa * ca.z, k3 = wa * ca.w;
                    acc[0].x += k0 * a0;  acc[0].y += k0 * a1;
                    acc[1].x += k1 * a0;  acc[1].y += k1 * a1;
                    acc[2].x += k2 * a0;  acc[2].y += k2 * a1;
                    acc[3].x += k3 * a0;  acc[3].y += k3 * a1;
                }
            }
            int sch = ch16 ^ (nl & 15);
            unsigned int base = nl * 128 + sch * 8 + (l & 3) * 2;   // ushort units
#pragma unroll
            for (int c = 0; c < 4; ++c) {
                unsigned int pk = (unsigned int)f2b(acc[c].x) | ((unsigned int)f2b(acc[c].y) << 16);
                *(unsigned int*)(Sl + c * 8192 + base) = pk;
            }
        }
    }
    __syncthreads();

    // ---------------- phase B ----------------
    const int quad = lane >> 4, lr = lane & 15;
    const int wr = wid & 1, wc = wid >> 1;           // 2 m-tiles x 4 n-tiles

    floatx4 acc[2][2];
#pragma unroll
    for (int i = 0; i < 2; ++i)
#pragma unroll
        for (int j = 0; j < 2; ++j) acc[i][j] = (floatx4)0.0f;

#pragma unroll
    for (int kc = 0; kc < 5; ++kc) {
#pragma unroll
        for (int ks = 0; ks < 4; ++ks) {
            bf16x8 a[2], b[2];
#pragma unroll
            for (int mi = 0; mi < 2; ++mi) {
                int nl = wr * 32 + mi * 16 + lr;
                if (kc < 4) {
                    int sch = (ks * 4 + quad) ^ (nl & 15);
                    a[mi] = *(const bf16x8*)(Sl + kc * 8192 + nl * 128 + sch * 8);
                } else {
                    int grow = rbase + nl;
                    if (grow >= N_NODES) grow = N_NODES - 1;   // clamp; rows>=N never stored
                    a[mi] = *(const bf16x8*)(X + (size_t)grow * 128 + ks * 32 + quad * 8);
                }
            }
#pragma unroll
            for (int j = 0; j < 2; ++j) {
                int n = wc * 32 + j * 16 + lr;
                b[j] = *(const bf16x8*)(WT + (size_t)n * 640 + kc * 128 + ks * 32 + quad * 8);
            }
#pragma unroll
            for (int mi = 0; mi < 2; ++mi)
#pragma unroll
                for (int j = 0; j < 2; ++j)
                    acc[mi][j] = __builtin_amdgcn_mfma_f32_16x16x32_bf16(a[mi], b[j], acc[mi][j], 0, 0, 0);
        }
    }

    // epilogue: C/D layout col=lane&15, row=quad*4+reg  [m89/m91-verified]
#pragma unroll
    for (int mi = 0; mi < 2; ++mi) {
#pragma unroll
        for (int reg = 0; reg < 4; ++reg) {
            int nl = wr * 32 + mi * 16 + quad * 4 + reg;
            int grow = rbase + nl;
            if (grow >= N_NODES) continue;
#pragma unroll
            for (int j = 0; j < 2; ++j) {
                int n = wc * 32 + j * 16 + lr;
                float v = acc[mi][j][reg] + bias[n];
                if (do_relu) v = v > 0.0f ? v : 0.0f;
                out[(size_t)grow * 128 + n] = f2b(v);
            }
        }
    }
}

// ---- DistMult score over dst-CSR: 1 wave/node, 16 lanes/edge -------------
__global__ __launch_bounds__(256) void k_score(const unsigned short* __restrict__ xf,
                                               const int4* __restrict__ edesc,
                                               const int* __restrict__ off,
                                               const unsigned short* __restrict__ relb,
                                               float* __restrict__ out) {
    int wid = threadIdx.x >> 6, lane = threadIdx.x & 63;
    int d = blockIdx.x * 4 + wid;
    if (d >= N_NODES) return;
    int p0 = off[d], p1 = off[d + 1];
    if (p0 == p1) return;
    int g = lane >> 4, li = lane & 15;
    uint4 bu = *(const uint4*)(xf + (size_t)d * 128 + li * 8);
    float bf[8];
    bf[0] = b2f(bu.x & 0xffffu); bf[1] = b2f(bu.x >> 16);
    bf[2] = b2f(bu.y & 0xffffu); bf[3] = b2f(bu.y >> 16);
    bf[4] = b2f(bu.z & 0xffffu); bf[5] = b2f(bu.z >> 16);
    bf[6] = b2f(bu.w & 0xffffu); bf[7] = b2f(bu.w >> 16);
    for (int p = p0 + g; p < p1; p += 4) {
        int4 e = edesc[p];
        uint4 au = *(const uint4*)(xf + (size_t)e.x * 128 + li * 8);
        uint4 ru = *(const uint4*)(relb + (size_t)e.y * 128 + li * 8);
        float v;
        v  = b2f(au.x & 0xffffu) * b2f(ru.x & 0xffffu) * bf[0];
        v += b2f(au.x >> 16)     * b2f(ru.x >> 16)     * bf[1];
        v += b2f(au.y & 0xffffu) * b2f(ru.y & 0xffffu) * bf[2];
        v += b2f(au.y >> 16)     * b2f(ru.y >> 16)     * bf[3];
        v += b2f(au.z & 0xffffu) * b2f(ru.z & 0xffffu) * bf[4];
        v += b2f(au.z >> 16)     * b2f(ru.z >> 16)     * bf[5];
        v += b2f(au.w & 0xffffu) * b2f(ru.w & 0xffffu) * bf[6];
        v += b2f(au.w >> 16)     * b2f(ru.w >> 16)     * bf[7];
        v += __shfl_xor(v, 8, 16);
        v += __shfl_xor(v, 4, 16);
        v += __shfl_xor(v, 2, 16);
        v += __shfl_xor(v, 1, 16);
        if (li == 0) out[e.z] = v;
    }
}

// ---- penalty = sum(rel^2), pure fp32 -------------------------------------
__global__ void k_penalty(const float* __restrict__ rel, float* __restrict__ out) {
    __shared__ float sm[256];
    float v = 0.0f;
    for (int i = threadIdx.x; i < RR * DIM; i += 256) { float x = rel[i]; v += x * x; }
    sm[threadIdx.x] = v;
    __syncthreads();
    for (int s = 128; s > 0; s >>= 1) {
        if (threadIdx.x < s) sm[threadIdx.x] += sm[threadIdx.x + s];
        __syncthreads();
    }
    if (threadIdx.x == 0) out[NE] = sm[0];
}

extern "C" void kernel_launch(void* const* d_in, const int* in_sizes, int n_in,
                              void* d_out, int out_size, void* d_ws, size_t ws_size,
                              hipStream_t stream) {
    (void)in_sizes; (void)n_in; (void)out_size; (void)ws_size;
    const int* edge_index = (const int*)d_in[0];
    const int* edge_type  = (const int*)d_in[1];
    const float* ent    = (const float*)d_in[2];
    const float* entb   = (const float*)d_in[3];
    const float* bases1 = (const float*)d_in[4];
    const float* comp1  = (const float*)d_in[5];
    const float* root1  = (const float*)d_in[6];
    const float* bias1  = (const float*)d_in[7];
    const float* bases2 = (const float*)d_in[8];
    const float* comp2  = (const float*)d_in[9];
    const float* root2  = (const float*)d_in[10];
    const float* bias2  = (const float*)d_in[11];
    const float* rel    = (const float*)d_in[12];
    const int* src = edge_index;
    const int* dst = edge_index + NE;

    char* ws = (char*)d_ws;
    size_t off_b = 0;
    auto alloc = [&](size_t bytes) { void* p = ws + off_b; off_b = (off_b + bytes + 255) & ~(size_t)255; return p; };

    unsigned short* x1   = (unsigned short*)alloc((size_t)N_NODES * 128 * 2);  // 25.6 MB
    unsigned short* x2   = (unsigned short*)alloc((size_t)N_NODES * 128 * 2);  // 25.6 MB
    unsigned short* wt1  = (unsigned short*)alloc(128 * 640 * 2);
    unsigned short* wt2  = (unsigned short*)alloc(128 * 640 * 2);
    unsigned short* relb = (unsigned short*)alloc(RR * DIM * 2);
    int*   deg    = (int*)alloc((size_t)N_NODES * 4);
    int*   cursor = (int*)alloc((size_t)N_NODES * 4);
    int*   offv   = (int*)alloc((size_t)(N_NODES + 1) * 4);
    int*   bsum   = (int*)alloc(NBLK * 4);
    int*   boff   = (int*)alloc(NBLK * 4);
    int4*  edesc  = (int4*)alloc((size_t)NE * 16);                             // 6.4 MB

    float* out = (float*)d_out;

    hipMemsetAsync(deg, 0, (size_t)N_NODES * 4, stream);
    hipMemsetAsync(cursor, 0, (size_t)N_NODES * 4, stream);

    k_deg<<<(NE + 255) / 256, 256, 0, stream>>>(dst, deg, NE);
    k_scan_block<<<NBLK, 256, 0, stream>>>(deg, bsum);
    k_scan_top<<<1, 256, 0, stream>>>(bsum, boff);
    k_scan_down<<<NBLK, 256, 0, stream>>>(deg, boff, offv);
    k_scatter<<<(NE + 255) / 256, 256, 0, stream>>>(src, dst, edge_type, offv, cursor, edesc, NE);
    k_norm2<<<(N_NODES + 255) / 256, 256, 0, stream>>>(offv, edesc);
    k_x0<<<(N_NODES * 128 + 255) / 256, 256, 0, stream>>>(ent, entb, x1, N_NODES * 128);
    k_prep<<<(128 * 640 + 255) / 256, 256, 0, stream>>>(bases1, root1, bases2, root2, rel,
                                                        wt1, wt2, relb);

    int fgrid = (N_NODES + 63) / 64;   // 1563
    // layer 1: x1 -> x2 (relu)
    k_fused<<<fgrid, 512, 0, stream>>>(x1, edesc, offv, comp1, wt1, bias1, x2, 1);
    // layer 2: x2 -> x1 (no relu); x1 becomes xf
    k_fused<<<fgrid, 512, 0, stream>>>(x2, edesc, offv, comp2, wt2, bias2, x1, 0);
    // decode
    k_score<<<(N_NODES + 3) / 4, 256, 0, stream>>>(x1, edesc, offv, relb, out);
    k_penalty<<<1, 256, 0, stream>>>(rel, out);
}